// Round 3
// baseline (195.960 us; speedup 1.0000x reference)
//
#include <hip/hip_runtime.h>
#include <math.h>

#define NB 8192      // batch rows
#define NC 1000      // classes
#define NF4 250      // NC / 4 float4s per row

// ws layout (floats, stride NB):
//  [0..4]   margin per branch
//  [5..9]   gathered (raw) per branch
//  [10..14] KD per branch
//  [15]     CE
//  [16]     row min of gathered over 4 real teachers
//  [17]     row max of row-maxes over 4 real teachers

#define LOG2E 1.4426950408889634f
#define LN2   0.6931471805599453f

__device__ __forceinline__ float fexp2(float x) { return __builtin_amdgcn_exp2f(x); }
__device__ __forceinline__ float flog2(float x) { return __builtin_amdgcn_logf(x); }

// Pin: force the loaded value to be materialized in VGPRs at this point.
// Defeats the compiler's load-sinking (R2 post-mortem: VGPR_Count=52 proved
// the 20-float4 hoist was silently undone -> only ~1 chunk in flight).
__device__ __forceinline__ void pin4(float4& v) {
  asm volatile("" : "+v"(v.x), "+v"(v.y), "+v"(v.z), "+v"(v.w));
}

// ---------------- DPP wave reductions (VALU pipe, not DS) ----------------
template <int CTRL>
__device__ __forceinline__ float dpp_mov(float v, float ident) {
  return __uint_as_float((unsigned)__builtin_amdgcn_update_dpp(
      (int)__float_as_uint(ident), (int)__float_as_uint(v), CTRL, 0xF, 0xF,
      false));
}

__device__ __forceinline__ float dppredsum(float v) {
  v += dpp_mov<0x111>(v, 0.f);
  v += dpp_mov<0x112>(v, 0.f);
  v += dpp_mov<0x114>(v, 0.f);
  v += dpp_mov<0x118>(v, 0.f);
  v += dpp_mov<0x142>(v, 0.f);
  v += dpp_mov<0x143>(v, 0.f);
  return v;  // lane 63 = full sum
}

__device__ __forceinline__ void dppredtop2(float& t1, float& t2) {
  const float NI = -INFINITY;
#define T2STEP(C)                                   \
  {                                                 \
    float i1 = dpp_mov<C>(t1, NI);                  \
    float i2 = dpp_mov<C>(t2, NI);                  \
    t2 = fmaxf(fmaxf(t2, i2), fminf(t1, i1));       \
    t1 = fmaxf(t1, i1);                             \
  }
  T2STEP(0x111) T2STEP(0x112) T2STEP(0x114) T2STEP(0x118)
  T2STEP(0x142) T2STEP(0x143)
#undef T2STEP
  // lane 63 = (max, runner-up)
}

// shfl-based helpers (only used in the small finalize kernel)
__device__ __forceinline__ float wredsum(float v) {
#pragma unroll
  for (int m = 32; m >= 1; m >>= 1) v += __shfl_xor(v, m, 64);
  return v;
}
__device__ __forceinline__ float wredmax(float v) {
#pragma unroll
  for (int m = 32; m >= 1; m >>= 1) v = fmaxf(v, __shfl_xor(v, m, 64));
  return v;
}
__device__ __forceinline__ float wredmin(float v) {
#pragma unroll
  for (int m = 32; m >= 1; m >>= 1) v = fminf(v, __shfl_xor(v, m, 64));
  return v;
}
__device__ __forceinline__ float f4get(const float4& v, int e) {
  return e == 0 ? v.x : e == 1 ? v.y : e == 2 ? v.z : v.w;
}

// Per-chunk accumulate (4 elements x 5 branches)
__device__ __forceinline__ void proc_chunk(
    const float4& c1, const float4& c2, const float4& c3, const float4& c4,
    const float4& cs, float t1[5], float t2[5], float Z[5], float S1[5],
    float& Z1, float& Z20) {
  const float K20 = LOG2E / 20.0f;
#pragma unroll
  for (int e = 0; e < 4; ++e) {
    float w0 = f4get(c1, e);
    float w1 = f4get(c2, e);
    float w2 = f4get(c3, e);
    float w3 = f4get(c4, e);
    float wsv = f4get(cs, e);
    float wm = ((w0 + w1) + w2 + w3) * 0.25f;  // mimic — keep this op order
    float w[5] = {w0, w1, w2, w3, wm};
#pragma unroll
    for (int t = 0; t < 5; ++t) {
      t2[t] = fmaxf(t2[t], fminf(t1[t], w[t]));
      t1[t] = fmaxf(t1[t], w[t]);
      float et = fexp2(w[t] * K20);
      Z[t] += et;
      S1[t] = fmaf(et, w[t] - wsv, S1[t]);
    }
    Z1 += fexp2(wsv * LOG2E);
    Z20 += fexp2(wsv * K20);
  }
}

// ONE WAVE per row; all 20 float4 loads issued back-to-back and PINNED so
// the compiler cannot sink them (one memory round-trip, 20 KB in flight per
// wave, ~320 KB per CU at 16 waves/CU). Gathers issued after the pin: their
// tg->gather dependent chain hides under the ~2600-cycle compute+reduction.
__global__ __launch_bounds__(256, 4) void k_rowstats(
    const float* __restrict__ o1, const float* __restrict__ o2,
    const float* __restrict__ o3, const float* __restrict__ o4,
    const float* __restrict__ os, const int* __restrict__ tg,
    float* __restrict__ ws, float* __restrict__ out) {
  const int lane = threadIdx.x & 63;
  const int wv = threadIdx.x >> 6;          // 0..3
  const int row = (blockIdx.x << 2) + wv;   // grid = NB/4
  const size_t base = (size_t)row * NC;

  // zero the output accumulator for k_final's atomics (runs strictly before)
  if (blockIdx.x == 0 && threadIdx.x == 0) out[0] = 0.0f;

  // bulk loads: 20 float4s, all issued before any wait
  float4 A1[4], A2[4], A3[4], A4[4], AS[4];
#pragma unroll
  for (int i = 0; i < 4; ++i) {
    int f = lane + (i << 6);
    if (f > NF4 - 1) f = NF4 - 1;           // clamp: safe dup load, masked below
    A1[i] = ((const float4*)(o1 + base))[f];
    A2[i] = ((const float4*)(o2 + base))[f];
    A3[i] = ((const float4*)(o3 + base))[f];
    A4[i] = ((const float4*)(o4 + base))[f];
    AS[i] = ((const float4*)(os + base))[f];
  }
  // force all 20 results live HERE -> loads cannot be sunk below this point
#pragma unroll
  for (int i = 0; i < 4; ++i) {
    pin4(A1[i]); pin4(A2[i]); pin4(A3[i]); pin4(A4[i]); pin4(AS[i]);
  }

  // target gathers: issued now, consumed only at the very end (lane 63)
  const int target = tg[row];
  const float g1 = o1[base + target];
  const float g2 = o2[base + target];
  const float g3 = o3[base + target];
  const float g4 = o4[base + target];
  const float gs = os[base + target];

  float t1[5], t2[5], Z[5], S1[5];
#pragma unroll
  for (int t = 0; t < 5; ++t) {
    t1[t] = -INFINITY; t2[t] = -INFINITY; Z[t] = 0.f; S1[t] = 0.f;
  }
  float Z1 = 0.f, Z20 = 0.f;

  proc_chunk(A1[0], A2[0], A3[0], A4[0], AS[0], t1, t2, Z, S1, Z1, Z20);
  proc_chunk(A1[1], A2[1], A3[1], A4[1], AS[1], t1, t2, Z, S1, Z1, Z20);
  proc_chunk(A1[2], A2[2], A3[2], A4[2], AS[2], t1, t2, Z, S1, Z1, Z20);
  if (lane < 58)  // chunk 3: f = lane+192 < 250
    proc_chunk(A1[3], A2[3], A3[3], A4[3], AS[3], t1, t2, Z, S1, Z1, Z20);

  // wave-level reductions on the VALU pipe (result in lane 63)
#pragma unroll
  for (int t = 0; t < 5; ++t) dppredtop2(t1[t], t2[t]);
#pragma unroll
  for (int t = 0; t < 5; ++t) { Z[t] = dppredsum(Z[t]); S1[t] = dppredsum(S1[t]); }
  Z1 = dppredsum(Z1);
  Z20 = dppredsum(Z20);

  if (lane == 63) {
    const float gm = ((g1 + g2) + g3 + g4) * 0.25f;  // same op order as wm
    float gg[5] = {g1, g2, g3, g4, gm};

    const float lse_s = flog2(Z20) * LN2;     // logsumexp(out_s/20), unshifted
    const float CE = flog2(Z1) * LN2 - gs;    // -log_softmax(out_s)[target]

#pragma unroll
    for (int t = 0; t < 5; ++t) {
      float lse_t = flog2(Z[t]) * LN2;
      float KD = 400.0f * (S1[t] / (20.0f * Z[t]) - lse_t + lse_s);
      float margin = (t1[t] == gg[t]) ? (t1[t] - t2[t]) : 0.0f;
      ws[(size_t)t * NB + row] = margin;
      ws[(size_t)(5 + t) * NB + row] = gg[t];
      ws[(size_t)(10 + t) * NB + row] = KD;
    }
    ws[(size_t)15 * NB + row] = CE;
    ws[(size_t)16 * NB + row] = fminf(fminf(g1, g2), fminf(g3, g4));
    ws[(size_t)17 * NB + row] = fmaxf(fmaxf(t1[0], t1[1]), fmaxf(t1[2], t1[3]));
  }
}

// Fused minmax + loss: every block REDUNDANTLY scans the 64 KB min/max
// columns (L2/L3-resident after k_rowstats -> ~free). Fully unrolled scan so
// all 16 loads are in flight (R2 had `unroll 1` -> 8 serialized round trips).
__global__ __launch_bounds__(256) void k_final(const float* __restrict__ ws,
                                               float* __restrict__ out) {
  const int tid = threadIdx.x;
  const int lane = tid & 63, wv = tid >> 6;
  __shared__ float sMn[4], sMx[4], sA[4];

  float mn = INFINITY, mx = -INFINITY;
  const float4* mnp = (const float4*)(ws + (size_t)16 * NB);
  const float4* mxp = (const float4*)(ws + (size_t)17 * NB);
#pragma unroll
  for (int k = 0; k < 8; ++k) {
    int r4 = tid + (k << 8);                // 8 x 256 = 2048 = NB/4
    float4 a = mnp[r4];
    float4 b = mxp[r4];
    mn = fminf(mn, fminf(fminf(a.x, a.y), fminf(a.z, a.w)));
    mx = fmaxf(mx, fmaxf(fmaxf(b.x, b.y), fmaxf(b.z, b.w)));
  }
  mn = wredmin(mn);
  mx = wredmax(mx);
  if (lane == 0) { sMn[wv] = mn; sMx[wv] = mx; }
  __syncthreads();
  const float a = fminf(fminf(sMn[0], sMn[1]), fminf(sMn[2], sMn[3]));
  const float b = fmaxf(fmaxf(sMx[0], sMx[1]), fmaxf(sMx[2], sMx[3]));
  const float shift = (a < 0.0f) ? (-a + 1e-5f) : 0.0f;
  const float maxp = b + shift;

  const int r = blockIdx.x * 256 + tid;   // 32 blocks x 256 = 8192 rows
  const float K6 = LOG2E / 6.0f;

  float m[5], e[5];
#pragma unroll
  for (int t = 0; t < 5; ++t) m[t] = ws[(size_t)t * NB + r];
  float pm = fmaxf(fmaxf(fmaxf(m[0], m[1]), fmaxf(m[2], m[3])), m[4]);
  float Zl = 0.0f;
#pragma unroll
  for (int t = 0; t < 5; ++t) { e[t] = fexp2((m[t] - pm) * K6); Zl += e[t]; }
  float ce = ws[(size_t)15 * NB + r];
  float rl = 0.0f;
#pragma unroll
  for (int t = 0; t < 5; ++t) {
    float g = ws[(size_t)(5 + t) * NB + r];
    float kd = ws[(size_t)(10 + t) * NB + r];
    float w2 = (g + shift) / maxp;
    float loss = (1.0f - w2) * ce + w2 * kd;
    rl += e[t] * loss;
  }
  float acc = rl / Zl;

  acc = wredsum(acc);
  if (lane == 0) sA[wv] = acc;
  __syncthreads();
  if (tid == 0) {
    float tot = (sA[0] + sA[1]) + (sA[2] + sA[3]);
    atomicAdd(out, tot * (1.0f / 8192.0f));
  }
}

extern "C" void kernel_launch(void* const* d_in, const int* in_sizes, int n_in,
                              void* d_out, int out_size, void* d_ws, size_t ws_size,
                              hipStream_t stream) {
  const float* o1 = (const float*)d_in[0];
  const float* o2 = (const float*)d_in[1];
  const float* o3 = (const float*)d_in[2];
  const float* o4 = (const float*)d_in[3];
  const float* os = (const float*)d_in[4];
  const int* tg = (const int*)d_in[5];
  float* ws = (float*)d_ws;
  float* out = (float*)d_out;

  k_rowstats<<<NB / 4, 256, 0, stream>>>(o1, o2, o3, o4, os, tg, ws, out);
  k_final<<<NB / 256, 256, 0, stream>>>(ws, out);
}

// Round 4
// 185.166 us; speedup vs baseline: 1.0583x; 1.0583x over previous
//
#include <hip/hip_runtime.h>
#include <math.h>

#define NB 8192      // batch rows
#define NC 1000      // classes
#define NF4 250      // NC / 4 float4s per row

// ws layout (floats, stride NB):
//  [0..4]   margin per branch
//  [5..9]   gathered (raw) per branch
//  [10..14] KD per branch
//  [15]     CE
//  [16]     row min of gathered over 4 real teachers
//  [17]     row max of row-maxes over 4 real teachers

#define LOG2E 1.4426950408889634f
#define LN2   0.6931471805599453f

__device__ __forceinline__ float fexp2(float x) { return __builtin_amdgcn_exp2f(x); }
__device__ __forceinline__ float flog2(float x) { return __builtin_amdgcn_logf(x); }

// Explicit counted waits (T4). Each followed by sched_barrier(0) so hipcc
// cannot hoist dependent ops above the wait (guide rule 18).
#define VMWAIT(N)                                        \
  asm volatile("s_waitcnt vmcnt(" #N ")" ::: "memory");  \
  __builtin_amdgcn_sched_barrier(0)
#define LGKM0                                            \
  asm volatile("s_waitcnt lgkmcnt(0)" ::: "memory");     \
  __builtin_amdgcn_sched_barrier(0)

// Direct global->LDS (zero VGPR payload, cannot be sunk/spilled by the
// compiler — R2 sank the hoisted loads, R3 spilled the pinned ones; this
// finally puts 20 KB/row in flight for real). LDS dest = uniform base +
// lane*16; global src is per-lane.
typedef const __attribute__((address_space(1))) unsigned int gu32;
typedef __attribute__((address_space(3))) unsigned int lu32;
__device__ __forceinline__ void stage16(const void* g, void* l) {
  __builtin_amdgcn_global_load_lds((gu32*)g, (lu32*)l, 16, 0, 0);
}

// ---------------- DPP wave reductions (VALU pipe, not DS) ----------------
template <int CTRL>
__device__ __forceinline__ float dpp_mov(float v, float ident) {
  return __uint_as_float((unsigned)__builtin_amdgcn_update_dpp(
      (int)__float_as_uint(ident), (int)__float_as_uint(v), CTRL, 0xF, 0xF,
      false));
}

__device__ __forceinline__ float dppredsum(float v) {
  v += dpp_mov<0x111>(v, 0.f);
  v += dpp_mov<0x112>(v, 0.f);
  v += dpp_mov<0x114>(v, 0.f);
  v += dpp_mov<0x118>(v, 0.f);
  v += dpp_mov<0x142>(v, 0.f);
  v += dpp_mov<0x143>(v, 0.f);
  return v;  // lane 63 = full sum
}

__device__ __forceinline__ void dppredtop2(float& t1, float& t2) {
  const float NI = -INFINITY;
#define T2STEP(C)                                   \
  {                                                 \
    float i1 = dpp_mov<C>(t1, NI);                  \
    float i2 = dpp_mov<C>(t2, NI);                  \
    t2 = fmaxf(fmaxf(t2, i2), fminf(t1, i1));       \
    t1 = fmaxf(t1, i1);                             \
  }
  T2STEP(0x111) T2STEP(0x112) T2STEP(0x114) T2STEP(0x118)
  T2STEP(0x142) T2STEP(0x143)
#undef T2STEP
  // lane 63 = (max, runner-up)
}

// shfl-based helpers (only used in the small finalize kernel)
__device__ __forceinline__ float wredsum(float v) {
#pragma unroll
  for (int m = 32; m >= 1; m >>= 1) v += __shfl_xor(v, m, 64);
  return v;
}
__device__ __forceinline__ float wredmax(float v) {
#pragma unroll
  for (int m = 32; m >= 1; m >>= 1) v = fmaxf(v, __shfl_xor(v, m, 64));
  return v;
}
__device__ __forceinline__ float wredmin(float v) {
#pragma unroll
  for (int m = 32; m >= 1; m >>= 1) v = fminf(v, __shfl_xor(v, m, 64));
  return v;
}
__device__ __forceinline__ float f4get(const float4& v, int e) {
  return e == 0 ? v.x : e == 1 ? v.y : e == 2 ? v.z : v.w;
}

// Per-chunk accumulate (4 elements x 5 branches)
__device__ __forceinline__ void proc_chunk(
    const float4& c1, const float4& c2, const float4& c3, const float4& c4,
    const float4& cs, float t1[5], float t2[5], float Z[5], float S1[5],
    float& Z1, float& Z20) {
  const float K20 = LOG2E / 20.0f;
#pragma unroll
  for (int e = 0; e < 4; ++e) {
    float w0 = f4get(c1, e);
    float w1 = f4get(c2, e);
    float w2 = f4get(c3, e);
    float w3 = f4get(c4, e);
    float wsv = f4get(cs, e);
    float wm = ((w0 + w1) + w2 + w3) * 0.25f;  // mimic — keep this op order
    float w[5] = {w0, w1, w2, w3, wm};
#pragma unroll
    for (int t = 0; t < 5; ++t) {
      t2[t] = fmaxf(t2[t], fminf(t1[t], w[t]));
      t1[t] = fmaxf(t1[t], w[t]);
      float et = fexp2(w[t] * K20);
      Z[t] += et;
      S1[t] = fmaf(et, w[t] - wsv, S1[t]);
    }
    Z1 += fexp2(wsv * LOG2E);
    Z20 += fexp2(wsv * K20);
  }
}

// ONE WAVE per row; row pipelined in 4 chunks of 5 KB via global_load_lds
// into double-buffered wave-private LDS (10 KB/wave, 40 KB/block ->
// 4 blocks/CU = 16 waves/CU). Counted vmcnt(5) waits keep one chunk always
// in flight per wave (~80 KB/CU steady-state). Wait counts assume ONLY the
// 5 stage-successors, so they stay correct wherever the compiler places the
// gather loads (extra outstanding ops can only over-wait).
__global__ __launch_bounds__(256, 4) void k_rowstats(
    const float* __restrict__ o1, const float* __restrict__ o2,
    const float* __restrict__ o3, const float* __restrict__ o4,
    const float* __restrict__ os, const int* __restrict__ tg,
    float* __restrict__ ws, float* __restrict__ out) {
  const int lane = threadIdx.x & 63;
  const int wv = threadIdx.x >> 6;          // 0..3
  const int row = (blockIdx.x << 2) + wv;   // grid = NB/4
  const size_t base = (size_t)row * NC;

  __shared__ float4 lds[4][2][5][64];       // [wave][buf][matrix][lane] 40 KB

  // zero the output accumulator for k_final's atomics (runs strictly before)
  if (blockIdx.x == 0 && threadIdx.x == 0) out[0] = 0.0f;

#define STAGE(i, b)                                                       \
  do {                                                                    \
    int f_ = lane + ((i) << 6);                                           \
    if (f_ > NF4 - 1) f_ = NF4 - 1; /* clamp: dup load, masked at c3 */   \
    stage16((const float4*)(o1 + base) + f_, &lds[wv][b][0][0]);          \
    stage16((const float4*)(o2 + base) + f_, &lds[wv][b][1][0]);          \
    stage16((const float4*)(o3 + base) + f_, &lds[wv][b][2][0]);          \
    stage16((const float4*)(o4 + base) + f_, &lds[wv][b][3][0]);          \
    stage16((const float4*)(os + base) + f_, &lds[wv][b][4][0]);          \
  } while (0)

  STAGE(0, 0);
  STAGE(1, 1);

  // target gathers: issued here, consumed only at the very end (lane 63)
  const int target = tg[row];
  const float g1 = o1[base + target];
  const float g2 = o2[base + target];
  const float g3 = o3[base + target];
  const float g4 = o4[base + target];
  const float gs = os[base + target];

  float t1[5], t2[5], Z[5], S1[5];
#pragma unroll
  for (int t = 0; t < 5; ++t) {
    t1[t] = -INFINITY; t2[t] = -INFINITY; Z[t] = 0.f; S1[t] = 0.f;
  }
  float Z1 = 0.f, Z20 = 0.f;
  float4 r1, r2, r3, r4, rs;

#define READC(b)                                                          \
  r1 = lds[wv][b][0][lane]; r2 = lds[wv][b][1][lane];                     \
  r3 = lds[wv][b][2][lane]; r4 = lds[wv][b][3][lane];                     \
  rs = lds[wv][b][4][lane];

  // ---- chunk 0 (buf 0); refill buf 0 with chunk 2 while computing ----
  VMWAIT(5);
  READC(0);
  LGKM0;               // chunk-0 data in VGPRs -> buf 0 free to overwrite
  STAGE(2, 0);
  proc_chunk(r1, r2, r3, r4, rs, t1, t2, Z, S1, Z1, Z20);

  // ---- chunk 1 (buf 1); refill buf 1 with chunk 3 ----
  VMWAIT(5);
  READC(1);
  LGKM0;
  STAGE(3, 1);
  proc_chunk(r1, r2, r3, r4, rs, t1, t2, Z, S1, Z1, Z20);

  // ---- chunk 2 (buf 0) ----
  VMWAIT(5);
  READC(0);
  LGKM0;
  proc_chunk(r1, r2, r3, r4, rs, t1, t2, Z, S1, Z1, Z20);

  // ---- chunk 3 (buf 1): f = lane+192, valid only for lane < 58 ----
  VMWAIT(0);
  READC(1);
  LGKM0;
  if (lane < 58)
    proc_chunk(r1, r2, r3, r4, rs, t1, t2, Z, S1, Z1, Z20);

  // wave-level reductions on the VALU pipe (result in lane 63)
#pragma unroll
  for (int t = 0; t < 5; ++t) dppredtop2(t1[t], t2[t]);
#pragma unroll
  for (int t = 0; t < 5; ++t) { Z[t] = dppredsum(Z[t]); S1[t] = dppredsum(S1[t]); }
  Z1 = dppredsum(Z1);
  Z20 = dppredsum(Z20);

  if (lane == 63) {
    const float gm = ((g1 + g2) + g3 + g4) * 0.25f;  // same op order as wm
    float gg[5] = {g1, g2, g3, g4, gm};

    const float lse_s = flog2(Z20) * LN2;     // logsumexp(out_s/20), unshifted
    const float CE = flog2(Z1) * LN2 - gs;    // -log_softmax(out_s)[target]

#pragma unroll
    for (int t = 0; t < 5; ++t) {
      float lse_t = flog2(Z[t]) * LN2;
      float KD = 400.0f * (S1[t] / (20.0f * Z[t]) - lse_t + lse_s);
      float margin = (t1[t] == gg[t]) ? (t1[t] - t2[t]) : 0.0f;
      ws[(size_t)t * NB + row] = margin;
      ws[(size_t)(5 + t) * NB + row] = gg[t];
      ws[(size_t)(10 + t) * NB + row] = KD;
    }
    ws[(size_t)15 * NB + row] = CE;
    ws[(size_t)16 * NB + row] = fminf(fminf(g1, g2), fminf(g3, g4));
    ws[(size_t)17 * NB + row] = fmaxf(fmaxf(t1[0], t1[1]), fmaxf(t1[2], t1[3]));
  }
#undef STAGE
#undef READC
}

// Fused minmax + loss: every block REDUNDANTLY scans the 64 KB min/max
// columns (L2/L3-resident after k_rowstats -> ~free). Fully unrolled scan so
// all 16 loads are in flight.
__global__ __launch_bounds__(256) void k_final(const float* __restrict__ ws,
                                               float* __restrict__ out) {
  const int tid = threadIdx.x;
  const int lane = tid & 63, wv = tid >> 6;
  __shared__ float sMn[4], sMx[4], sA[4];

  float mn = INFINITY, mx = -INFINITY;
  const float4* mnp = (const float4*)(ws + (size_t)16 * NB);
  const float4* mxp = (const float4*)(ws + (size_t)17 * NB);
#pragma unroll
  for (int k = 0; k < 8; ++k) {
    int r4 = tid + (k << 8);                // 8 x 256 = 2048 = NB/4
    float4 a = mnp[r4];
    float4 b = mxp[r4];
    mn = fminf(mn, fminf(fminf(a.x, a.y), fminf(a.z, a.w)));
    mx = fmaxf(mx, fmaxf(fmaxf(b.x, b.y), fmaxf(b.z, b.w)));
  }
  mn = wredmin(mn);
  mx = wredmax(mx);
  if (lane == 0) { sMn[wv] = mn; sMx[wv] = mx; }
  __syncthreads();
  const float a = fminf(fminf(sMn[0], sMn[1]), fminf(sMn[2], sMn[3]));
  const float b = fmaxf(fmaxf(sMx[0], sMx[1]), fmaxf(sMx[2], sMx[3]));
  const float shift = (a < 0.0f) ? (-a + 1e-5f) : 0.0f;
  const float maxp = b + shift;

  const int r = blockIdx.x * 256 + tid;   // 32 blocks x 256 = 8192 rows
  const float K6 = LOG2E / 6.0f;

  float m[5], e[5];
#pragma unroll
  for (int t = 0; t < 5; ++t) m[t] = ws[(size_t)t * NB + r];
  float pm = fmaxf(fmaxf(fmaxf(m[0], m[1]), fmaxf(m[2], m[3])), m[4]);
  float Zl = 0.0f;
#pragma unroll
  for (int t = 0; t < 5; ++t) { e[t] = fexp2((m[t] - pm) * K6); Zl += e[t]; }
  float ce = ws[(size_t)15 * NB + r];
  float rl = 0.0f;
#pragma unroll
  for (int t = 0; t < 5; ++t) {
    float g = ws[(size_t)(5 + t) * NB + r];
    float kd = ws[(size_t)(10 + t) * NB + r];
    float w2 = (g + shift) / maxp;
    float loss = (1.0f - w2) * ce + w2 * kd;
    rl += e[t] * loss;
  }
  float acc = rl / Zl;

  acc = wredsum(acc);
  if (lane == 0) sA[wv] = acc;
  __syncthreads();
  if (tid == 0) {
    float tot = (sA[0] + sA[1]) + (sA[2] + sA[3]);
    atomicAdd(out, tot * (1.0f / 8192.0f));
  }
}

extern "C" void kernel_launch(void* const* d_in, const int* in_sizes, int n_in,
                              void* d_out, int out_size, void* d_ws, size_t ws_size,
                              hipStream_t stream) {
  const float* o1 = (const float*)d_in[0];
  const float* o2 = (const float*)d_in[1];
  const float* o3 = (const float*)d_in[2];
  const float* o4 = (const float*)d_in[3];
  const float* os = (const float*)d_in[4];
  const int* tg = (const int*)d_in[5];
  float* ws = (float*)d_ws;
  float* out = (float*)d_out;

  k_rowstats<<<NB / 4, 256, 0, stream>>>(o1, o2, o3, o4, os, tg, ws, out);
  k_final<<<NB / 256, 256, 0, stream>>>(ws, out);
}